// Round 3
// baseline (354.386 us; speedup 1.0000x reference)
//
#include <hip/hip_runtime.h>

typedef _Float16 f16;
typedef _Float16 f16x8 __attribute__((ext_vector_type(8)));
typedef _Float16 f16x4 __attribute__((ext_vector_type(4)));
typedef float    f32x4 __attribute__((ext_vector_type(4)));

#define MFMA16(a, b, c) __builtin_amdgcn_mfma_f32_16x16x32_f16((a), (b), (c), 0, 0, 0)

constexpr int T = 64;    // sequence length
constexpr int C = 384;   // n_embd
constexpr int H = 64;    // head size
constexpr float SCALE = 3.26598632371090f;  // 64 * 384^-0.5

// async global->LDS, 16B per lane; LDS dest = wave-uniform base + lane*16
__device__ __forceinline__ void load_lds16(const float* g, float* l) {
  __builtin_amdgcn_global_load_lds(
      (const __attribute__((address_space(1))) void*)g,
      (__attribute__((address_space(3))) void*)l, 16, 0, 0);
}

// ---------------------------------------------------------------------------
// Pack Wk,Wq,Wv (fp32 [64][384]) into f16 MFMA-fragment order (kt-major):
//   tile2 = kt*12 + wi*4 + ht      (wi: 0=K,1=Q,2=V; combo = wi*4+ht)
//   Wp[tile2*512 + lane*8 + j] = W_wi[16*ht + (lane&15)][32*kt + 8*(lane>>4) + j]
// ---------------------------------------------------------------------------
__global__ void pack_w(const float* __restrict__ Wk, const float* __restrict__ Wq,
                       const float* __restrict__ Wv, f16* __restrict__ Wp) {
  int tid = blockIdx.x * blockDim.x + threadIdx.x;
  if (tid >= 3 * 12 * 4 * 64) return;
  int lane = tid & 63;
  int tile = tid >> 6;
  int ht = tile & 3;
  int kt = (tile >> 2) % 12;
  int wi = tile / 48;
  const float* W = (wi == 0) ? Wk : ((wi == 1) ? Wq : Wv);
  int h = 16 * ht + (lane & 15);
  int c = 32 * kt + 8 * (lane >> 4);
  const float* src = W + h * C + c;
  f16x8 v;
#pragma unroll
  for (int j = 0; j < 8; ++j) v[j] = (f16)src[j];
  int tile2 = kt * 12 + wi * 4 + ht;   // kt-major store
  *(f16x8*)(Wp + (size_t)tile2 * 512 + lane * 8) = v;
}

// ---------------------------------------------------------------------------
// Kernel A (R7): QKV projection only. One block per batch, 4 waves.
// Phase-1 math is R5's verified code verbatim (xc fragment-interleave, wave
// w owns combos 3w..3w+2, all 4 row-tiles). Schedule = minimum 2-phase:
// STAGE(next) issued FIRST, then ds_read+cvt+MFMA on cur, then ONE trailing
// vmcnt(0)+raw barrier per K-step (stage loads get the whole compute phase
// to land; 16 waves/CU of TLP hides the rest).
// Epilogue: K/Q -> global f16 [b][t][h] directly (f16x4-contiguous).
//           V -> vT LDS overlay (reusing dead xc space) -> coalesced store
//           to vtg[b][h][t]. LDS total 16.5 KB -> no LDS occupancy cap.
// ---------------------------------------------------------------------------
__global__ __launch_bounds__(256, 4) void proj_kqv(
    const float* __restrict__ x, const f16* __restrict__ Wp,
    f16* __restrict__ kg, f16* __restrict__ qg, f16* __restrict__ vtg) {
  __shared__ float xc[2][2048];   // 16 KB staging; vT overlay after phase 1

  const int b = blockIdx.x;
  const int tid = threadIdx.x;
  const int w = tid >> 6;       // wave 0..3
  const int lane = tid & 63;
  const int l15 = lane & 15;
  const int g = lane >> 4;      // quad 0..3

  const f32x4 vzero = {0.0f, 0.0f, 0.0f, 0.0f};
  f32x4 acc[3][4];              // combo c = 3w+c, row-tile tt
#pragma unroll
  for (int c = 0; c < 3; ++c)
#pragma unroll
    for (int tt = 0; tt < 4; ++tt) acc[c][tt] = vzero;

  const f16* wp_base[3];
  bool isV[3];
#pragma unroll
  for (int c = 0; c < 3; ++c) {
    int combo = 3 * w + c;
    wp_base[c] = Wp + (size_t)combo * 512 + lane * 8;  // kt stride = 12*512
    isV[c] = (combo >= 8);
  }

  const float* xbase = x + (size_t)b * T * C;
  // Wave w stages rows [16w,16w+16); instr j=2w+half covers LDS
  // [j*1024,(j+1)*1024) = 64 lanes x 16B. Layout (R5, verified):
  // xc[(tt*2+half)*256 + lane*4 + j] = x[16tt+(lane&15)][kt*32+(lane>>4)*8+half*4+j]
  const float* gsrc = xbase + (size_t)(16 * w + l15) * C + g * 8;

  // ---- prologue: stage chunk 0, load Wp(kt=0) frags
  load_lds16(gsrc + 0, &xc[0][(2 * w + 0) * 256]);
  load_lds16(gsrc + 4, &xc[0][(2 * w + 1) * 256]);
  f16x8 wpc[3], wpn[3];
#pragma unroll
  for (int c = 0; c < 3; ++c) wpc[c] = *(const f16x8*)(wp_base[c]);
  asm volatile("s_waitcnt vmcnt(0)" ::: "memory");
  __builtin_amdgcn_s_barrier();

  // ---- 12 K-steps, 2-phase: stage-first / compute / drain-late
#pragma unroll
  for (int kt = 0; kt < 12; ++kt) {
    const int cur = kt & 1;
    if (kt + 1 < 12) {
      load_lds16(gsrc + (kt + 1) * 32 + 0, &xc[cur ^ 1][(2 * w + 0) * 256]);
      load_lds16(gsrc + (kt + 1) * 32 + 4, &xc[cur ^ 1][(2 * w + 1) * 256]);
#pragma unroll
      for (int c = 0; c < 3; ++c)
        wpn[c] = *(const f16x8*)(wp_base[c] + (size_t)(kt + 1) * 6144);
    }

    f16x8 xf[4];
#pragma unroll
    for (int tt = 0; tt < 4; ++tt) {
      f32x4 A0 = *(const f32x4*)&xc[cur][(2 * tt + 0) * 256 + lane * 4];
      f32x4 A1 = *(const f32x4*)&xc[cur][(2 * tt + 1) * 256 + lane * 4];
#pragma unroll
      for (int j = 0; j < 4; ++j) { xf[tt][j] = (f16)A0[j]; xf[tt][4 + j] = (f16)A1[j]; }
    }
#pragma unroll
    for (int c = 0; c < 3; ++c) {
      f16x8 wf = wpc[c];
      if (!isV[c]) {  // K or Q: D[h][t] (W as A, x as B)
#pragma unroll
        for (int tt = 0; tt < 4; ++tt) acc[c][tt] = MFMA16(wf, xf[tt], acc[c][tt]);
      } else {        // V: D[t][h] (x as A, W as B)
#pragma unroll
        for (int tt = 0; tt < 4; ++tt) acc[c][tt] = MFMA16(xf[tt], wf, acc[c][tt]);
      }
      wpc[c] = wpn[c];
    }
    // trailing drain: stage of kt+1 (issued at top) has had the whole
    // compute phase to complete; one barrier per K-step.
    asm volatile("s_waitcnt vmcnt(0)" ::: "memory");
    __builtin_amdgcn_s_barrier();
  }

  // ---- epilogue: K/Q direct to global; V via LDS overlay (xc is dead)
  f16* vt_lds = (f16*)&xc[0][0];  // [64][68] f16, pitch 68 (<=2-way banks)
#pragma unroll
  for (int c = 0; c < 3; ++c) {
    int combo = 3 * w + c;
    int m = combo >> 2;
    int ht = combo & 3;
#pragma unroll
    for (int tt = 0; tt < 4; ++tt) {
      f16x4 pd;
#pragma unroll
      for (int r = 0; r < 4; ++r) pd[r] = (f16)acc[c][tt][r];
      if (m == 0) {        // K: D[h][t], t=16tt+l15, h=16ht+4g+r (contig)
        *(f16x4*)(kg + ((size_t)b * 64 + 16 * tt + l15) * 64 + 16 * ht + 4 * g) = pd;
      } else if (m == 1) { // Q: same layout
        *(f16x4*)(qg + ((size_t)b * 64 + 16 * tt + l15) * 64 + 16 * ht + 4 * g) = pd;
      } else {             // V: D[t][h] -> vT[h][t]: h=16ht+l15, t=16tt+4g+r
        *(f16x4*)&vt_lds[(16 * ht + l15) * 68 + 16 * tt + 4 * g] = pd;
      }
    }
  }
  __syncthreads();
  // coalesced vT store: vtg[b][h][t], linear f16x8: idx = h*8+seg
#pragma unroll
  for (int r = 0; r < 2; ++r) {
    int idx = tid + r * 256;
    f16x8 vv = *(const f16x8*)&vt_lds[(idx >> 3) * 68 + (idx & 7) * 8];
    *(f16x8*)(vtg + (size_t)b * 4096 + idx * 8) = vv;
  }
}

// ---------------------------------------------------------------------------
// Kernel B (R7): attention per batch. One block per batch, 4 waves,
// 27.6 KB LDS -> 5 blocks/CU. Stages k/q/vT tiles (perfectly linear f16x8
// global loads: row*64+seg*8 == idx*8) into the pitch-72 LDS layout, then
// phases 2-4 + store VERBATIM from the verified fused kernel.
// ---------------------------------------------------------------------------
__global__ __launch_bounds__(256, 5) void attn64(
    const f16* __restrict__ kg, const f16* __restrict__ qg,
    const f16* __restrict__ vtg, float* __restrict__ out) {
  // pitch 72 f16 = 36 dwords; 36 % 32 = 4 -> <=2-way LDS bank aliasing (free)
  __shared__ f16 qp_lds[64][72];  // phase 2: q[t][h]; phases 3-4: P[t][s]
  __shared__ f16 k_lds[64][72];   // k[t][h]
  __shared__ f16 vT_lds[64][72];  // v^T[h][t]

  const int b = blockIdx.x;
  const int tid = threadIdx.x;
  const int w = tid >> 6;
  const int lane = tid & 63;
  const int l15 = lane & 15;
  const int g = lane >> 4;
  const int t_ = 16 * w + l15;

  // ---- stage: 6 independent 16B loads, then 6 LDS writes
  const size_t tb = (size_t)b * 4096;
  const int i0 = tid, i1 = tid + 256;
  f16x8 ka = *(const f16x8*)(kg + tb + (size_t)i0 * 8);
  f16x8 kb = *(const f16x8*)(kg + tb + (size_t)i1 * 8);
  f16x8 qa = *(const f16x8*)(qg + tb + (size_t)i0 * 8);
  f16x8 qb = *(const f16x8*)(qg + tb + (size_t)i1 * 8);
  f16x8 va = *(const f16x8*)(vtg + tb + (size_t)i0 * 8);
  f16x8 vb = *(const f16x8*)(vtg + tb + (size_t)i1 * 8);
  *(f16x8*)&k_lds[i0 >> 3][(i0 & 7) * 8] = ka;
  *(f16x8*)&k_lds[i1 >> 3][(i1 & 7) * 8] = kb;
  *(f16x8*)&qp_lds[i0 >> 3][(i0 & 7) * 8] = qa;
  *(f16x8*)&qp_lds[i1 >> 3][(i1 & 7) * 8] = qb;
  *(f16x8*)&vT_lds[i0 >> 3][(i0 & 7) * 8] = va;
  *(f16x8*)&vT_lds[i1 >> 3][(i1 & 7) * 8] = vb;
  __syncthreads();

  const f32x4 vzero = {0.0f, 0.0f, 0.0f, 0.0f};

  // ---- Phase 2: S^T = k.q^T  (lane holds column t_ of S, 16 s-entries)
  f32x4 accs[4];
#pragma unroll
  for (int i = 0; i < 4; ++i) accs[i] = vzero;
#pragma unroll
  for (int kt = 0; kt < 2; ++kt) {
    f16x8 qf = *(const f16x8*)&qp_lds[t_][32 * kt + 8 * g];
#pragma unroll
    for (int mt = 0; mt < 4; ++mt) {
      f16x8 kf = *(const f16x8*)&k_lds[16 * mt + l15][32 * kt + 8 * g];
      accs[mt] = MFMA16(kf, qf, accs[mt]);  // D[s][t]: s = 16mt+4g+r, t = t_
    }
  }

  // ---- Phase 3: causal mask + softmax over s (per column t_, fp32)
  float e[16];
  float mx = -__builtin_inff();
#pragma unroll
  for (int mt = 0; mt < 4; ++mt) {
#pragma unroll
    for (int r = 0; r < 4; ++r) {
      int s = 16 * mt + 4 * g + r;
      float lv = accs[mt][r] * SCALE;
      lv = (s <= t_) ? lv : -__builtin_inff();
      e[mt * 4 + r] = lv;
      mx = fmaxf(mx, lv);
    }
  }
  mx = fmaxf(mx, __shfl_xor(mx, 16));
  mx = fmaxf(mx, __shfl_xor(mx, 32));
  float sm = 0.0f;
#pragma unroll
  for (int i = 0; i < 16; ++i) { e[i] = __expf(e[i] - mx); sm += e[i]; }
  sm += __shfl_xor(sm, 16);
  sm += __shfl_xor(sm, 32);
  const float inv = 1.0f / sm;
  // P overwrites qp_lds rows [16w,16w+16): wave-private rows; all other
  // waves' post-barrier qp_lds reads are own-row only. No barrier needed.
#pragma unroll
  for (int mt = 0; mt < 4; ++mt) {
    f16x4 pp;
#pragma unroll
    for (int r = 0; r < 4; ++r) pp[r] = (f16)(e[mt * 4 + r] * inv);
    *(f16x4*)&qp_lds[t_][16 * mt + 4 * g] = pp;  // P[t][s], s = 16mt+4g+r
  }

  // ---- Phase 4: out^T = v^T . P^T  (A = vT, B-frag from P[t][s])
  f32x4 acco[4];
#pragma unroll
  for (int i = 0; i < 4; ++i) acco[i] = vzero;
#pragma unroll
  for (int kt = 0; kt < 2; ++kt) {
    f16x8 pf = *(const f16x8*)&qp_lds[t_][32 * kt + 8 * g];
#pragma unroll
    for (int mt = 0; mt < 4; ++mt) {
      f16x8 vf = *(const f16x8*)&vT_lds[16 * mt + l15][32 * kt + 8 * g];
      acco[mt] = MFMA16(vf, pf, acco[mt]);  // D[h][t]: h = 16mt+4g+r, t = t_
    }
  }

  // ---- store: out[b][t][h] fp32, 4 consecutive h per reg quad -> float4
  float* orow = out + ((size_t)b * T + t_) * H;
#pragma unroll
  for (int mt = 0; mt < 4; ++mt) {
    *(f32x4*)(orow + 16 * mt + 4 * g) = acco[mt];
  }
}

extern "C" void kernel_launch(void* const* d_in, const int* in_sizes, int n_in,
                              void* d_out, int out_size, void* d_ws, size_t ws_size,
                              hipStream_t stream) {
  const float* x  = (const float*)d_in[0];
  const float* Wk = (const float*)d_in[1];
  const float* Wq = (const float*)d_in[2];
  const float* Wv = (const float*)d_in[3];
  float* out = (float*)d_out;

  // workspace layout: Wp (147456 B, padded to 256 KiB) | kg | qg | vtg
  f16* Wp  = (f16*)d_ws;
  f16* kg  = (f16*)((char*)d_ws + (1 << 18));
  f16* qg  = kg + (size_t)2048 * 64 * 64;   // 16 MiB each
  f16* vtg = qg + (size_t)2048 * 64 * 64;

  pack_w<<<36, 256, 0, stream>>>(Wk, Wq, Wv, Wp);
  proj_kqv<<<2048, 256, 0, stream>>>(x, Wp, kg, qg, vtg);
  attn64<<<2048, 256, 0, stream>>>(kg, qg, vtg, out);
}